// Round 3
// baseline (1915.054 us; speedup 1.0000x reference)
//
#include <hip/hip_runtime.h>

#define D       256
#define NHEADS  8
#define DH      32
#define FFDIM   1024
#define VOCAB   2048
#define GENLEN  16
#define BATCH   8
#define NSLOT   7
#define TF      17
#define NLAYER  4

#define SCOPE_AGENT __HIP_MEMORY_SCOPE_AGENT

struct Params {
  // inputs
  const float *slots, *W_slot_proj, *dict_emb, *pe;
  const float *ln_self_w, *ln_self_b, *Wq_s, *Wk_s, *Wv_s, *Wo_s;
  const float *ln_cross_w, *ln_cross_b, *Wq_c, *Wk_c, *Wv_c, *Wo_c;
  const float *ln_ffn_w, *ln_ffn_b, *W1, *b1, *W2, *b2;
  const float *ln_f_w, *ln_f_b, *W_out;
  // workspace
  float *enc, *Kc, *Vc, *kcache, *vcache, *logits;
  float *X0, *X1, *P0, *P1;
  unsigned long long *bars;   // one 64B-padded slot per batch group
  // outputs
  float *out_z, *out_lp;
};

// coherent (agent-scope, cache-bypassing) accessors for cross-block data
__device__ __forceinline__ float cload(const float* p) {
  return __hip_atomic_load(p, __ATOMIC_RELAXED, SCOPE_AGENT);
}
__device__ __forceinline__ void cstore(float* p, float v) {
  __hip_atomic_store(p, v, __ATOMIC_RELAXED, SCOPE_AGENT);
}

__device__ __forceinline__ float blockSum(float v, float* red) {
  #pragma unroll
  for (int o = 32; o > 0; o >>= 1) v += __shfl_down(v, o);
  const int lane = threadIdx.x & 63, w = threadIdx.x >> 6;
  if (lane == 0) red[w] = v;
  __syncthreads();
  float s = red[0] + red[1] + red[2] + red[3];
  __syncthreads();
  return s;
}

__global__ __launch_bounds__(256) void mega_kernel(Params p)
{
  const int blk = blockIdx.x;
  const int b = blk >> 3, sl = blk & 7, tid = threadIdx.x;
  unsigned long long* bar = p.bars + b * 8;   // 64 B apart per batch group
  unsigned target = 0;

  __shared__ float hsh[D], qsh[DH], osh[DH], score[TF], red[4];
  __shared__ float sval[256];
  __shared__ int   sidx[256];
  __shared__ float ash[128];
  __shared__ float pool[2048];   // logits staging / enc staging / scratch

  // ---- per-batch-group barrier: 8 blocks, packed {gen:hi32, arrive:lo32} ----
  auto gbar = [&]() {
    ++target;
    __syncthreads();   // drains this block's vmem (stores retired to coherence point)
    if (tid == 0) {
      unsigned long long old =
          __hip_atomic_fetch_add(bar, 1ull, __ATOMIC_RELAXED, SCOPE_AGENT);
      if ((old & 0xffffffffull) == 7ull) {
        // 8th arriver: reset count and publish generation in ONE atomic store
        __hip_atomic_store(bar, ((unsigned long long)target) << 32,
                           __ATOMIC_RELAXED, SCOPE_AGENT);
      } else {
        while ((unsigned)(__hip_atomic_load(bar, __ATOMIC_RELAXED, SCOPE_AGENT) >> 32)
               < target)
          __builtin_amdgcn_s_sleep(2);
      }
    }
    __syncthreads();
    asm volatile("" ::: "memory");   // compiler: no load motion across the barrier
  };

  // ================= init: enc = slots @ W_slot_proj (slice cols) =================
  if (tid < 32) {
    const int c = sl * 32 + tid;
    float acc[NSLOT] = {0.f,0.f,0.f,0.f,0.f,0.f,0.f};
    for (int i = 0; i < D; ++i) {
      const float w = p.W_slot_proj[i * D + c];
      #pragma unroll
      for (int s = 0; s < NSLOT; ++s) acc[s] += p.slots[(b * NSLOT + s) * D + i] * w;
    }
    for (int s = 0; s < NSLOT; ++s) cstore(&p.enc[(b * NSLOT + s) * D + c], acc[s]);
  }
  gbar();

  // ================= init: Kc/Vc slice cols (block-local consumers) ================
  {
    for (int i = tid; i < NSLOT * D; i += 256) pool[i] = cload(&p.enc[b * NSLOT * D + i]);
    __syncthreads();
    const int l = tid >> 6, c32 = (tid & 63) >> 1, mat = tid & 1;
    const int c = sl * DH + c32;
    const float* W = (mat ? p.Wv_c : p.Wk_c) + l * D * D + c;
    float acc[NSLOT] = {0.f,0.f,0.f,0.f,0.f,0.f,0.f};
    for (int i = 0; i < D; ++i) {
      const float w = W[i * D];
      #pragma unroll
      for (int s = 0; s < NSLOT; ++s) acc[s] += pool[s * D + i] * w;
    }
    float* dst = (mat ? p.Vc : p.Kc) + ((l * BATCH + b) * NSLOT) * D + c;
    for (int s = 0; s < NSLOT; ++s) dst[s * D] = acc[s];   // normal store: same-block reader
    __syncthreads();
  }

  float* Xb[2] = {p.X0, p.X1};
  float* Pb[2] = {p.P0, p.P1};
  int par = 0;

  // ================================ generation loop ================================
  for (int t = 0; t < GENLEN; ++t) {
    for (int l = 0; l < NLAYER; ++l) {
      // ------------------------------- SELF-ATTN -------------------------------
      {
        float xv;
        if (l == 0) {
          int tok = 0;
          if (t > 0) {
            const float* lg = p.logits + b * VOCAB;
            for (int c = tid; c < VOCAB; c += 256) pool[c] = cload(&lg[c]);
            __syncthreads();
            float m = -1e30f; int mi = 0;
            for (int c = tid; c < VOCAB; c += 256) { float v = pool[c]; if (v > m) { m = v; mi = c; } }
            sval[tid] = m; sidx[tid] = mi;
            __syncthreads();
            for (int s = 128; s; s >>= 1) {
              if (tid < s) {
                float v2 = sval[tid + s]; int i2 = sidx[tid + s];
                if (v2 > sval[tid] || (v2 == sval[tid] && i2 < sidx[tid])) { sval[tid] = v2; sidx[tid] = i2; }
              }
              __syncthreads();
            }
            const float mx = sval[0]; const int amax = sidx[0];
            __syncthreads();
            float ssum = 0.f;
            for (int c = tid; c < VOCAB; c += 256) ssum += expf(pool[c] - mx);
            const float tot = blockSum(ssum, red);
            const float lse = mx + logf(tot);
            p.out_lp[(b * GENLEN + (t - 1)) * VOCAB + sl * 256 + tid] = pool[sl * 256 + tid] - lse;
            if (sl == 0 && tid == 0)
              p.out_z[b * VOCAB * GENLEN + amax * GENLEN + (t - 1)] = 1.0f;
            tok = amax + 1;   // BOS column prepended
            __syncthreads();  // pool free before any reuse
          }
          xv = p.dict_emb[tok * D + tid] + p.pe[t * D + tid];
        } else {
          xv = cload(&Xb[par][b * D + tid]);
          #pragma unroll
          for (int i = 0; i < 8; ++i) xv += cload(&Pb[par][(b * 8 + i) * D + tid]);
        }

        const float mean = blockSum(xv, red) * (1.f / D);
        const float dv = xv - mean;
        const float var = blockSum(dv * dv, red) * (1.f / D);
        const float hval = dv * (1.f / sqrtf(var + 1e-5f)) * p.ln_self_w[l * D + tid]
                         + p.ln_self_b[l * D + tid];
        hsh[tid] = hval;
        // SLATE quirk: layer 0 replaces residual stream with LN output
        if (sl == 0) cstore(&Xb[par ^ 1][b * D + tid], (l == 0) ? hval : xv);
        __syncthreads();

        if (tid < 96) {
          const int mm = tid >> 5, c32 = tid & 31, c = sl * DH + c32;
          const float* W = (mm == 0 ? p.Wq_s : (mm == 1 ? p.Wk_s : p.Wv_s)) + l * D * D + c;
          float a0 = 0.f, a1 = 0.f, a2 = 0.f, a3 = 0.f;
          for (int i = 0; i < D; i += 4) {
            a0 += hsh[i]     * W[i * D];
            a1 += hsh[i + 1] * W[(i + 1) * D];
            a2 += hsh[i + 2] * W[(i + 2) * D];
            a3 += hsh[i + 3] * W[(i + 3) * D];
          }
          const float acc = (a0 + a1) + (a2 + a3);
          if (mm == 0)      qsh[c32] = acc * 0.17677669529663689f;  // dh^-0.5
          else if (mm == 1) p.kcache[((l * BATCH + b) * TF + t) * D + c] = acc;
          else              p.vcache[((l * BATCH + b) * TF + t) * D + c] = acc;
        }
        __syncthreads();

        if (tid <= t) {
          const float* kk = p.kcache + ((l * BATCH + b) * TF + tid) * D + sl * DH;
          float acc = 0.f;
          #pragma unroll
          for (int r = 0; r < DH; ++r) acc += qsh[r] * kk[r];
          score[tid] = acc;
        }
        __syncthreads();
        if (tid == 0) {
          float mx = -1e30f;
          for (int i = 0; i <= t; ++i) mx = fmaxf(mx, score[i]);
          float s2 = 0.f;
          for (int i = 0; i <= t; ++i) { const float e = expf(score[i] - mx); score[i] = e; s2 += e; }
          const float inv = 1.f / s2;
          for (int i = 0; i <= t; ++i) score[i] *= inv;
        }
        __syncthreads();
        if (tid < DH) {
          float acc = 0.f;
          for (int pp = 0; pp <= t; ++pp)
            acc += score[pp] * p.vcache[((l * BATCH + b) * TF + pp) * D + sl * DH + tid];
          osh[tid] = acc;
        }
        __syncthreads();
        {
          const float* Wo = p.Wo_s + l * D * D + sl * DH * D + tid;
          float a0 = 0.f;
          #pragma unroll
          for (int r = 0; r < DH; ++r) a0 += osh[r] * Wo[r * D];
          cstore(&Pb[par ^ 1][(b * 8 + sl) * D + tid], a0);
        }
      }
      gbar(); par ^= 1;

      // ------------------------------- CROSS-ATTN -------------------------------
      {
        float xv = cload(&Xb[par][b * D + tid]);
        #pragma unroll
        for (int i = 0; i < 8; ++i) xv += cload(&Pb[par][(b * 8 + i) * D + tid]);
        if (sl == 0) cstore(&Xb[par ^ 1][b * D + tid], xv);

        const float mean = blockSum(xv, red) * (1.f / D);
        const float dv = xv - mean;
        const float var = blockSum(dv * dv, red) * (1.f / D);
        hsh[tid] = dv * (1.f / sqrtf(var + 1e-5f)) * p.ln_cross_w[l * D + tid]
                 + p.ln_cross_b[l * D + tid];
        __syncthreads();

        if (tid < DH) {
          const int c = sl * DH + tid;
          const float* W = p.Wq_c + l * D * D + c;
          float a0 = 0.f, a1 = 0.f, a2 = 0.f, a3 = 0.f;
          for (int i = 0; i < D; i += 4) {
            a0 += hsh[i]     * W[i * D];
            a1 += hsh[i + 1] * W[(i + 1) * D];
            a2 += hsh[i + 2] * W[(i + 2) * D];
            a3 += hsh[i + 3] * W[(i + 3) * D];
          }
          qsh[tid] = ((a0 + a1) + (a2 + a3)) * 0.17677669529663689f;
        }
        __syncthreads();
        if (tid < NSLOT) {
          const float* kk = p.Kc + ((l * BATCH + b) * NSLOT + tid) * D + sl * DH;
          float acc = 0.f;
          #pragma unroll
          for (int r = 0; r < DH; ++r) acc += qsh[r] * kk[r];
          score[tid] = acc;
        }
        __syncthreads();
        if (tid == 0) {
          float mx = -1e30f;
          for (int i = 0; i < NSLOT; ++i) mx = fmaxf(mx, score[i]);
          float s2 = 0.f;
          for (int i = 0; i < NSLOT; ++i) { const float e = expf(score[i] - mx); score[i] = e; s2 += e; }
          const float inv = 1.f / s2;
          for (int i = 0; i < NSLOT; ++i) score[i] *= inv;
        }
        __syncthreads();
        if (tid < DH) {
          float acc = 0.f;
          #pragma unroll
          for (int s = 0; s < NSLOT; ++s)
            acc += score[s] * p.Vc[((l * BATCH + b) * NSLOT + s) * D + sl * DH + tid];
          osh[tid] = acc;
        }
        __syncthreads();
        {
          const float* Wo = p.Wo_c + l * D * D + sl * DH * D + tid;
          float a0 = 0.f;
          #pragma unroll
          for (int r = 0; r < DH; ++r) a0 += osh[r] * Wo[r * D];
          cstore(&Pb[par ^ 1][(b * 8 + sl) * D + tid], a0);
        }
      }
      gbar(); par ^= 1;

      // ---------------------------------- FFN ----------------------------------
      {
        float xv = cload(&Xb[par][b * D + tid]);
        #pragma unroll
        for (int i = 0; i < 8; ++i) xv += cload(&Pb[par][(b * 8 + i) * D + tid]);
        if (sl == 0) cstore(&Xb[par ^ 1][b * D + tid], xv);

        const float mean = blockSum(xv, red) * (1.f / D);
        const float dv = xv - mean;
        const float var = blockSum(dv * dv, red) * (1.f / D);
        hsh[tid] = dv * (1.f / sqrtf(var + 1e-5f)) * p.ln_ffn_w[l * D + tid]
                 + p.ln_ffn_b[l * D + tid];
        __syncthreads();

        if (tid < 128) {
          const int c = sl * 128 + tid;
          const float* W = p.W1 + l * D * FFDIM + c;
          float a0 = 0.f, a1 = 0.f, a2 = 0.f, a3 = 0.f;
          for (int i = 0; i < D; i += 4) {
            a0 += hsh[i]     * W[i * FFDIM];
            a1 += hsh[i + 1] * W[(i + 1) * FFDIM];
            a2 += hsh[i + 2] * W[(i + 2) * FFDIM];
            a3 += hsh[i + 3] * W[(i + 3) * FFDIM];
          }
          ash[tid] = fmaxf(((a0 + a1) + (a2 + a3)) + p.b1[l * FFDIM + c], 0.f);
        }
        __syncthreads();

        float acc = (sl == 0) ? p.b2[l * D + tid] : 0.f;
        const float* W2 = p.W2 + l * FFDIM * D + sl * 128 * D + tid;
        for (int r = 0; r < 128; ++r) acc += ash[r] * W2[r * D];
        cstore(&Pb[par ^ 1][(b * 8 + sl) * D + tid], acc);
        __syncthreads();   // ash stable until all threads done
      }
      gbar(); par ^= 1;
    }

    // --------------------------------- LOGITS ---------------------------------
    {
      float xv = cload(&Xb[par][b * D + tid]);
      #pragma unroll
      for (int i = 0; i < 8; ++i) xv += cload(&Pb[par][(b * 8 + i) * D + tid]);
      const float mean = blockSum(xv, red) * (1.f / D);
      const float dv = xv - mean;
      const float var = blockSum(dv * dv, red) * (1.f / D);
      hsh[tid] = dv * (1.f / sqrtf(var + 1e-5f)) * p.ln_f_w[tid] + p.ln_f_b[tid];
      __syncthreads();
      const int c = sl * 256 + tid;
      const float* W = p.W_out + c;
      float a0 = 0.f, a1 = 0.f, a2 = 0.f, a3 = 0.f;
      for (int i = 0; i < D; i += 4) {
        a0 += hsh[i]     * W[i * VOCAB];
        a1 += hsh[i + 1] * W[(i + 1) * VOCAB];
        a2 += hsh[i + 2] * W[(i + 2) * VOCAB];
        a3 += hsh[i + 3] * W[(i + 3) * VOCAB];
      }
      cstore(&p.logits[b * VOCAB + c], (a0 + a1) + (a2 + a3));
      __syncthreads();   // hsh stable until all threads done
    }
    gbar();
  }

  // ------------------------------ final step output ------------------------------
  {
    const float* lg = p.logits + b * VOCAB;
    for (int c = tid; c < VOCAB; c += 256) pool[c] = cload(&lg[c]);
    __syncthreads();
    float m = -1e30f; int mi = 0;
    for (int c = tid; c < VOCAB; c += 256) { float v = pool[c]; if (v > m) { m = v; mi = c; } }
    sval[tid] = m; sidx[tid] = mi;
    __syncthreads();
    for (int s = 128; s; s >>= 1) {
      if (tid < s) {
        float v2 = sval[tid + s]; int i2 = sidx[tid + s];
        if (v2 > sval[tid] || (v2 == sval[tid] && i2 < sidx[tid])) { sval[tid] = v2; sidx[tid] = i2; }
      }
      __syncthreads();
    }
    const float mx = sval[0]; const int amax = sidx[0];
    __syncthreads();
    float ssum = 0.f;
    for (int c = tid; c < VOCAB; c += 256) ssum += expf(pool[c] - mx);
    const float tot = blockSum(ssum, red);
    const float lse = mx + logf(tot);
    p.out_lp[(b * GENLEN + (GENLEN - 1)) * VOCAB + sl * 256 + tid] = pool[sl * 256 + tid] - lse;
    if (sl == 0 && tid == 0)
      p.out_z[b * VOCAB * GENLEN + amax * GENLEN + (GENLEN - 1)] = 1.0f;
  }
}

extern "C" void kernel_launch(void* const* d_in, const int* in_sizes, int n_in,
                              void* d_out, int out_size, void* d_ws, size_t ws_size,
                              hipStream_t stream)
{
  Params p;
  const float* const* in = (const float* const*)d_in;
  p.slots = in[0];  p.W_slot_proj = in[1]; p.dict_emb = in[2]; p.pe = in[3];
  p.ln_self_w = in[4];  p.ln_self_b = in[5];
  p.Wq_s = in[6];  p.Wk_s = in[7];  p.Wv_s = in[8];  p.Wo_s = in[9];
  p.ln_cross_w = in[10]; p.ln_cross_b = in[11];
  p.Wq_c = in[12]; p.Wk_c = in[13]; p.Wv_c = in[14]; p.Wo_c = in[15];
  p.ln_ffn_w = in[16]; p.ln_ffn_b = in[17];
  p.W1 = in[18]; p.b1 = in[19]; p.W2 = in[20]; p.b2 = in[21];
  p.ln_f_w = in[22]; p.ln_f_b = in[23]; p.W_out = in[24];

  // workspace layout: barriers first (64 B per batch group, 8-byte aligned base)
  p.bars = (unsigned long long*)d_ws;
  float* ws = (float*)d_ws + BATCH * 8 * 2;            // 8 ull = 16 floats per group
  p.enc = ws;    ws += BATCH * NSLOT * D;
  p.Kc = ws;     ws += NLAYER * BATCH * NSLOT * D;
  p.Vc = ws;     ws += NLAYER * BATCH * NSLOT * D;
  p.kcache = ws; ws += NLAYER * BATCH * TF * D;
  p.vcache = ws; ws += NLAYER * BATCH * TF * D;
  p.X0 = ws;     ws += BATCH * D;
  p.X1 = ws;     ws += BATCH * D;
  p.P0 = ws;     ws += BATCH * 8 * D;
  p.P1 = ws;     ws += BATCH * 8 * D;
  p.logits = ws; ws += BATCH * VOCAB;

  p.out_z = (float*)d_out;
  p.out_lp = (float*)d_out + BATCH * VOCAB * GENLEN;

  hipMemsetAsync(d_ws, 0, BATCH * 8 * sizeof(unsigned long long), stream);  // barriers
  hipMemsetAsync(d_out, 0, (size_t)out_size * sizeof(float), stream);       // one-hot zeros

  mega_kernel<<<64, 256, 0, stream>>>(p);
}